// Round 5
// baseline (219.466 us; speedup 1.0000x reference)
//
#include <hip/hip_runtime.h>
#include <hip/hip_bf16.h>

#define B_SZ 2
#define H_SZ 16
#define S_SZ 2048
#define D_SZ 64
#define WAVES 8
#define NBH  (B_SZ * H_SZ)      // 32
#define NQB  (S_SZ / 16)        // 128 16-row blocks
#define NUB  (S_SZ / 32)        // 64 32-row V blocks

typedef __bf16 bf16x8 __attribute__((ext_vector_type(8)));
typedef float  f32x4  __attribute__((ext_vector_type(4)));

// d_ws layout: pre-swizzled bf16 MFMA fragments (8 MB segments)
#define SEG   (8u * 1024u * 1024u)
#define QHI_OFF (0 * (size_t)SEG)
#define QLO_OFF (1 * (size_t)SEG)
#define KHI_OFF (2 * (size_t)SEG)
#define KLO_OFF (3 * (size_t)SEG)
#define VSW_OFF (4 * (size_t)SEG)

// ---- prep Q/K: fp32 -> bf16 hi/lo, swizzled to A/B fragment order.
__global__ __launch_bounds__(256) void prep_qk(
    const float* __restrict__ Q, const float* __restrict__ K,
    char* __restrict__ ws)
{
    const int lane = threadIdx.x & 63;
    const int wv   = threadIdx.x >> 6;
    const int l15  = lane & 15;
    const int g    = lane >> 4;
    const int wid  = blockIdx.x * 4 + wv;          // 0..8191
    const int tensor = wid >> 12;
    const int rem  = wid & 4095;
    const int bh   = rem >> 7;
    const int blk  = rem & 127;

    const float* src = (tensor ? K : Q) + ((size_t)bh * S_SZ + blk * 16 + l15) * D_SZ;
    bf16x8* hi = (bf16x8*)(ws + (tensor ? KHI_OFF : QHI_OFF));
    bf16x8* lo = (bf16x8*)(ws + (tensor ? KLO_OFF : QLO_OFF));

    #pragma unroll
    for (int ks = 0; ks < 2; ++ks) {
        const float* p = src + 32 * ks + 8 * g;
        f32x4 a = *(const f32x4*)p;
        f32x4 b = *(const f32x4*)(p + 4);
        bf16x8 vh, vl;
        #pragma unroll
        for (int j = 0; j < 4; ++j) {
            __bf16 h0 = (__bf16)a[j];
            __bf16 h1 = (__bf16)b[j];
            vh[j]     = h0;
            vh[4 + j] = h1;
            vl[j]     = (__bf16)(a[j] - (float)h0);
            vl[4 + j] = (__bf16)(b[j] - (float)h1);
        }
        size_t di = ((size_t)(bh * NQB + blk) * 2 + ks) * 64 + lane;
        hi[di] = vh;
        lo[di] = vl;
    }
}

// ---- prep V: fp32 -> bf16, B-fragment order with pi-permutation baked in.
__global__ __launch_bounds__(256) void prep_v(
    const float* __restrict__ V, char* __restrict__ ws)
{
    __shared__ float vt[4][32 * 68];
    const int lane = threadIdx.x & 63;
    const int wv   = threadIdx.x >> 6;
    const int l15  = lane & 15;
    const int g    = lane >> 4;
    const int wid  = blockIdx.x * 4 + wv;          // 0..2047
    const int bh   = wid >> 6;
    const int u    = wid & 63;

    const float* src = V + ((size_t)bh * S_SZ + u * 32) * D_SZ;
    float* t = vt[wv];
    #pragma unroll
    for (int i = 0; i < 8; ++i) {
        int idx = i * 64 + lane;
        int row = idx >> 4;
        int c4  = idx & 15;
        *(f32x4*)(t + row * 68 + c4 * 4) = *(const f32x4*)(src + row * 64 + c4 * 4);
    }
    __syncthreads();

    bf16x8* vsw = (bf16x8*)(ws + VSW_OFF);
    #pragma unroll
    for (int db = 0; db < 4; ++db) {
        bf16x8 vb;
        #pragma unroll
        for (int j = 0; j < 8; ++j) {
            int kk = (j < 4) ? (4 * g + j) : (16 + 4 * g + (j - 4));
            vb[j] = (__bf16)t[kk * 68 + 16 * db + l15];
        }
        vsw[((size_t)(bh * NUB + u) * 4 + db) * 64 + lane] = vb;
    }
}

// ---- main fused kernel: 2 q-tiles (32 q-rows) per workgroup.
// Each wave computes BOTH q-tiles against its 256-col k-slice, so every
// K/V fragment load feeds 2x the MFMAs -> L2 read traffic halved.
// ~196 unified regs -> __launch_bounds__(512,2): 8 waves/CU.
__global__ __launch_bounds__(512, 2) void attn_fused3(
    const char* __restrict__ ws, float* __restrict__ OutC, float* __restrict__ OutW)
{
    __shared__ float redm[WAVES][32];
    __shared__ float reds[WAVES][32];
    __shared__ float ctxred[WAVES][32][D_SZ];   // 64 KB

    const int tid  = threadIdx.x;
    const int lane = tid & 63;
    const int wv   = tid >> 6;
    const int l15  = lane & 15;
    const int g    = lane >> 4;

    // XCD-aware swizzle: XCD x owns bh range [4x, 4x+4)
    const int b    = blockIdx.x;
    const int work = (b & 7) * 256 + (b >> 3);
    const int bh   = work >> 6;
    const int qt   = work & 63;          // 32-row tile index
    const int q0   = qt * 32;

    const bf16x8* QHI = (const bf16x8*)(ws + QHI_OFF);
    const bf16x8* QLO = (const bf16x8*)(ws + QLO_OFF);
    const bf16x8* KHI = (const bf16x8*)(ws + KHI_OFF);
    const bf16x8* KLO = (const bf16x8*)(ws + KLO_OFF);
    const bf16x8* VSW = (const bf16x8*)(ws + VSW_OFF);

    float* Wb = OutW + (size_t)bh * S_SZ * S_SZ;
    float* Cb = OutC + (size_t)bh * S_SZ * D_SZ;

    // Q fragments for both 16-row tiles
    bf16x8 qhi0[2], qlo0[2], qhi1[2], qlo1[2];
    {
        size_t qi = ((size_t)(bh * NQB + 2 * qt) * 2) * 64 + lane;
        qhi0[0] = QHI[qi];        qhi0[1] = QHI[qi + 64];
        qlo0[0] = QLO[qi];        qlo0[1] = QLO[qi + 64];
        qhi1[0] = QHI[qi + 128];  qhi1[1] = QHI[qi + 192];
        qlo1[0] = QLO[qi + 128];  qlo1[1] = QLO[qi + 192];
    }

    // QK^T: 16 col-blocks per wave; K loaded once, 12 MFMA per block
    f32x4 s0[16], s1[16];
    const int kb0 = wv * 16;
    #pragma unroll
    for (int cb = 0; cb < 16; ++cb) {
        size_t bi = ((size_t)(bh * NQB + kb0 + cb) * 2) * 64 + lane;
        bf16x8 kh0 = KHI[bi], kh1 = KHI[bi + 64];
        bf16x8 kl0 = KLO[bi], kl1 = KLO[bi + 64];
        f32x4 a0 = {0.f, 0.f, 0.f, 0.f};
        f32x4 a1 = {0.f, 0.f, 0.f, 0.f};
        a0 = __builtin_amdgcn_mfma_f32_16x16x32_bf16(kh0, qhi0[0], a0, 0, 0, 0);
        a1 = __builtin_amdgcn_mfma_f32_16x16x32_bf16(kh0, qhi1[0], a1, 0, 0, 0);
        a0 = __builtin_amdgcn_mfma_f32_16x16x32_bf16(kh0, qlo0[0], a0, 0, 0, 0);
        a1 = __builtin_amdgcn_mfma_f32_16x16x32_bf16(kh0, qlo1[0], a1, 0, 0, 0);
        a0 = __builtin_amdgcn_mfma_f32_16x16x32_bf16(kl0, qhi0[0], a0, 0, 0, 0);
        a1 = __builtin_amdgcn_mfma_f32_16x16x32_bf16(kl0, qhi1[0], a1, 0, 0, 0);
        a0 = __builtin_amdgcn_mfma_f32_16x16x32_bf16(kh1, qhi0[1], a0, 0, 0, 0);
        a1 = __builtin_amdgcn_mfma_f32_16x16x32_bf16(kh1, qhi1[1], a1, 0, 0, 0);
        a0 = __builtin_amdgcn_mfma_f32_16x16x32_bf16(kh1, qlo0[1], a0, 0, 0, 0);
        a1 = __builtin_amdgcn_mfma_f32_16x16x32_bf16(kh1, qlo1[1], a1, 0, 0, 0);
        a0 = __builtin_amdgcn_mfma_f32_16x16x32_bf16(kl1, qhi0[1], a0, 0, 0, 0);
        a1 = __builtin_amdgcn_mfma_f32_16x16x32_bf16(kl1, qhi1[1], a1, 0, 0, 0);
        s0[cb] = a0;
        s1[cb] = a1;
    }

    // row max (both tiles)
    float m0 = -3.0e38f, m1 = -3.0e38f;
    #pragma unroll
    for (int cb = 0; cb < 16; ++cb) {
        #pragma unroll
        for (int r = 0; r < 4; ++r) {
            m0 = fmaxf(m0, s0[cb][r]);
            m1 = fmaxf(m1, s1[cb][r]);
        }
    }
    m0 = fmaxf(m0, __shfl_xor(m0, 16));
    m0 = fmaxf(m0, __shfl_xor(m0, 32));
    m1 = fmaxf(m1, __shfl_xor(m1, 16));
    m1 = fmaxf(m1, __shfl_xor(m1, 32));
    if (lane < 16) {
        redm[wv][l15]      = m0;
        redm[wv][16 + l15] = m1;
    }
    __syncthreads();
    float mall0 = redm[0][l15],      mall1 = redm[0][16 + l15];
    #pragma unroll
    for (int w2 = 1; w2 < WAVES; ++w2) {
        mall0 = fmaxf(mall0, redm[w2][l15]);
        mall1 = fmaxf(mall1, redm[w2][16 + l15]);
    }

    // exp + row sum
    float sm0 = 0.f, sm1 = 0.f;
    #pragma unroll
    for (int cb = 0; cb < 16; ++cb) {
        #pragma unroll
        for (int r = 0; r < 4; ++r) {
            float e0 = __expf(s0[cb][r] - mall0);
            float e1 = __expf(s1[cb][r] - mall1);
            s0[cb][r] = e0;
            s1[cb][r] = e1;
            sm0 += e0;
            sm1 += e1;
        }
    }
    sm0 += __shfl_xor(sm0, 16);
    sm0 += __shfl_xor(sm0, 32);
    sm1 += __shfl_xor(sm1, 16);
    sm1 += __shfl_xor(sm1, 32);
    if (lane < 16) {
        reds[wv][l15]      = sm0;
        reds[wv][16 + l15] = sm1;
    }
    __syncthreads();
    float ls0 = 0.f, ls1 = 0.f;
    #pragma unroll
    for (int w2 = 0; w2 < WAVES; ++w2) {
        ls0 += reds[w2][l15];
        ls1 += reds[w2][16 + l15];
    }
    const float inv0 = 1.0f / ls0;
    const float inv1 = 1.0f / ls1;

    // fused: normalize -> NT store W -> pack P to bf16 (frees s0/s1 before PV)
    bf16x8 pa0[8], pa1[8];
    float* wrow0 = Wb + (size_t)(q0 + l15) * S_SZ + wv * 256;
    float* wrow1 = wrow0 + (size_t)16 * S_SZ;
    #pragma unroll
    for (int u = 0; u < 8; ++u) {
        f32x4 w00, w01, w10, w11;
        #pragma unroll
        for (int r = 0; r < 4; ++r) {
            w00[r] = s0[2 * u][r]     * inv0;
            w01[r] = s0[2 * u + 1][r] * inv0;
            w10[r] = s1[2 * u][r]     * inv1;
            w11[r] = s1[2 * u + 1][r] * inv1;
        }
        __builtin_nontemporal_store(w00, (f32x4*)(wrow0 + (2 * u) * 16 + 4 * g));
        __builtin_nontemporal_store(w01, (f32x4*)(wrow0 + (2 * u + 1) * 16 + 4 * g));
        __builtin_nontemporal_store(w10, (f32x4*)(wrow1 + (2 * u) * 16 + 4 * g));
        __builtin_nontemporal_store(w11, (f32x4*)(wrow1 + (2 * u + 1) * 16 + 4 * g));
        #pragma unroll
        for (int r = 0; r < 4; ++r) {
            pa0[u][r]     = (__bf16)w00[r];
            pa0[u][4 + r] = (__bf16)w01[r];
            pa1[u][r]     = (__bf16)w10[r];
            pa1[u][4 + r] = (__bf16)w11[r];
        }
    }

    // PV: V loaded once, used for both tiles
    f32x4 ctx0[4], ctx1[4];
    #pragma unroll
    for (int db = 0; db < 4; ++db) {
        ctx0[db] = (f32x4){0.f, 0.f, 0.f, 0.f};
        ctx1[db] = (f32x4){0.f, 0.f, 0.f, 0.f};
    }
    #pragma unroll
    for (int u = 0; u < 8; ++u) {
        size_t vbase = ((size_t)(bh * NUB + wv * 8 + u) * 4) * 64 + lane;
        #pragma unroll
        for (int db = 0; db < 4; ++db) {
            bf16x8 vb = VSW[vbase + (size_t)db * 64];
            ctx0[db] = __builtin_amdgcn_mfma_f32_16x16x32_bf16(pa0[u], vb, ctx0[db], 0, 0, 0);
            ctx1[db] = __builtin_amdgcn_mfma_f32_16x16x32_bf16(pa1[u], vb, ctx1[db], 0, 0, 0);
        }
    }

    // cross-wave context reduction (both tiles)
    #pragma unroll
    for (int db = 0; db < 4; ++db) {
        #pragma unroll
        for (int r = 0; r < 4; ++r) {
            ctxred[wv][4 * g + r][16 * db + l15]        = ctx0[db][r];
            ctxred[wv][16 + 4 * g + r][16 * db + l15]   = ctx1[db][r];
        }
    }
    __syncthreads();
    {
        const int qr = tid >> 6;    // 0..7
        const int d  = tid & 63;
        #pragma unroll
        for (int half = 0; half < 4; ++half) {
            const int row = qr + 8 * half;
            float acc = 0.f;
            #pragma unroll
            for (int w2 = 0; w2 < WAVES; ++w2) acc += ctxred[w2][row][d];
            __builtin_nontemporal_store(acc, Cb + (size_t)(q0 + row) * D_SZ + d);
        }
    }
}

extern "C" void kernel_launch(void* const* d_in, const int* in_sizes, int n_in,
                              void* d_out, int out_size, void* d_ws, size_t ws_size,
                              hipStream_t stream)
{
    const float* Q = (const float*)d_in[0];
    const float* K = (const float*)d_in[1];
    const float* V = (const float*)d_in[2];
    float* ctx = (float*)d_out;
    float* w   = (float*)d_out + (size_t)B_SZ * H_SZ * S_SZ * D_SZ;
    char*  ws  = (char*)d_ws;

    prep_qk<<<2048, 256, 0, stream>>>(Q, K, ws);
    prep_v <<<512,  256, 0, stream>>>(V, ws);
    attn_fused3<<<2048, 512, 0, stream>>>(ws, ctx, w);
}

// Round 6
// 184.971 us; speedup vs baseline: 1.1865x; 1.1865x over previous
//
#include <hip/hip_runtime.h>
#include <hip/hip_bf16.h>

#define B_SZ 2
#define H_SZ 16
#define S_SZ 2048
#define D_SZ 64
#define WAVES 8
#define NBH  (B_SZ * H_SZ)      // 32
#define NQB  (S_SZ / 16)        // 128 16-row blocks
#define NUB  (S_SZ / 32)        // 64 32-row V blocks

typedef __bf16 bf16x8 __attribute__((ext_vector_type(8)));
typedef float  f32x4  __attribute__((ext_vector_type(4)));

// d_ws layout: pre-swizzled bf16 MFMA fragments (8 MB segments)
#define SEG   (8u * 1024u * 1024u)
#define QHI_OFF (0 * (size_t)SEG)
#define QLO_OFF (1 * (size_t)SEG)
#define KHI_OFF (2 * (size_t)SEG)
#define KLO_OFF (3 * (size_t)SEG)
#define VSW_OFF (4 * (size_t)SEG)

// ---- prep Q/K: fp32 -> bf16 hi/lo, swizzled to A/B fragment order.
__global__ __launch_bounds__(256) void prep_qk(
    const float* __restrict__ Q, const float* __restrict__ K,
    char* __restrict__ ws)
{
    const int lane = threadIdx.x & 63;
    const int wv   = threadIdx.x >> 6;
    const int l15  = lane & 15;
    const int g    = lane >> 4;
    const int wid  = blockIdx.x * 4 + wv;          // 0..8191
    const int tensor = wid >> 12;
    const int rem  = wid & 4095;
    const int bh   = rem >> 7;
    const int blk  = rem & 127;

    const float* src = (tensor ? K : Q) + ((size_t)bh * S_SZ + blk * 16 + l15) * D_SZ;
    bf16x8* hi = (bf16x8*)(ws + (tensor ? KHI_OFF : QHI_OFF));
    bf16x8* lo = (bf16x8*)(ws + (tensor ? KLO_OFF : QLO_OFF));

    #pragma unroll
    for (int ks = 0; ks < 2; ++ks) {
        const float* p = src + 32 * ks + 8 * g;
        f32x4 a = *(const f32x4*)p;
        f32x4 b = *(const f32x4*)(p + 4);
        bf16x8 vh, vl;
        #pragma unroll
        for (int j = 0; j < 4; ++j) {
            __bf16 h0 = (__bf16)a[j];
            __bf16 h1 = (__bf16)b[j];
            vh[j]     = h0;
            vh[4 + j] = h1;
            vl[j]     = (__bf16)(a[j] - (float)h0);
            vl[4 + j] = (__bf16)(b[j] - (float)h1);
        }
        size_t di = ((size_t)(bh * NQB + blk) * 2 + ks) * 64 + lane;
        hi[di] = vh;
        lo[di] = vl;
    }
}

// ---- prep V: fp32 -> bf16, B-fragment order with pi-permutation baked in.
__global__ __launch_bounds__(256) void prep_v(
    const float* __restrict__ V, char* __restrict__ ws)
{
    __shared__ float vt[4][32 * 68];
    const int lane = threadIdx.x & 63;
    const int wv   = threadIdx.x >> 6;
    const int l15  = lane & 15;
    const int g    = lane >> 4;
    const int wid  = blockIdx.x * 4 + wv;          // 0..2047
    const int bh   = wid >> 6;
    const int u    = wid & 63;

    const float* src = V + ((size_t)bh * S_SZ + u * 32) * D_SZ;
    float* t = vt[wv];
    #pragma unroll
    for (int i = 0; i < 8; ++i) {
        int idx = i * 64 + lane;
        int row = idx >> 4;
        int c4  = idx & 15;
        *(f32x4*)(t + row * 68 + c4 * 4) = *(const f32x4*)(src + row * 64 + c4 * 4);
    }
    __syncthreads();

    bf16x8* vsw = (bf16x8*)(ws + VSW_OFF);
    #pragma unroll
    for (int db = 0; db < 4; ++db) {
        bf16x8 vb;
        #pragma unroll
        for (int j = 0; j < 8; ++j) {
            int kk = (j < 4) ? (4 * g + j) : (16 + 4 * g + (j - 4));
            vb[j] = (__bf16)t[kk * 68 + 16 * db + l15];
        }
        vsw[((size_t)(bh * NUB + u) * 4 + db) * 64 + lane] = vb;
    }
}

// ---- main fused kernel (R4 structure + LDS-staged row-major W write-out).
// W tile staged in LDS as bf16 [16][2048] (64 KB, XOR-swizzled 8B units),
// then swept out row-major: each store instr = 1 KB contiguous, each wg
// writes its 131 KB W-slab sequentially (DRAM page friendly).
__global__ __launch_bounds__(512, 4) void attn_fused4(
    const char* __restrict__ ws, float* __restrict__ OutC, float* __restrict__ OutW)
{
    __shared__ __align__(16) char smem[66560];   // 64KB W-tile + redm + reds
    float* redm = (float*)(smem + 65536);        // [8][16]
    float* reds = (float*)(smem + 65536 + 512);  // [8][16]

    const int tid  = threadIdx.x;
    const int lane = tid & 63;
    const int wv   = tid >> 6;
    const int l15  = lane & 15;
    const int g    = lane >> 4;

    // XCD-aware swizzle: XCD x owns bh range [4x, 4x+4)
    const int b    = blockIdx.x;
    const int work = (b & 7) * 512 + (b >> 3);
    const int bh   = work >> 7;
    const int qt   = work & 127;
    const int q0   = qt * 16;

    const bf16x8* QHI = (const bf16x8*)(ws + QHI_OFF);
    const bf16x8* QLO = (const bf16x8*)(ws + QLO_OFF);
    const bf16x8* KHI = (const bf16x8*)(ws + KHI_OFF);
    const bf16x8* KLO = (const bf16x8*)(ws + KLO_OFF);
    const bf16x8* VSW = (const bf16x8*)(ws + VSW_OFF);

    float* Wb = OutW + (size_t)bh * S_SZ * S_SZ;
    float* Cb = OutC + (size_t)bh * S_SZ * D_SZ;

    // Q fragments
    bf16x8 qhi[2], qlo[2];
    {
        size_t qi = ((size_t)(bh * NQB + qt) * 2) * 64 + lane;
        qhi[0] = QHI[qi];       qhi[1] = QHI[qi + 64];
        qlo[0] = QLO[qi];       qlo[1] = QLO[qi + 64];
    }

    // QK^T: 16 col-blocks per wave, 6 MFMA each (3-term bf16 split)
    f32x4 s[16];
    const int kb0 = wv * 16;
    #pragma unroll
    for (int cb = 0; cb < 16; ++cb) {
        size_t bi = ((size_t)(bh * NQB + kb0 + cb) * 2) * 64 + lane;
        bf16x8 kh0 = KHI[bi], kh1 = KHI[bi + 64];
        bf16x8 kl0 = KLO[bi], kl1 = KLO[bi + 64];
        f32x4 acc = {0.f, 0.f, 0.f, 0.f};
        acc = __builtin_amdgcn_mfma_f32_16x16x32_bf16(kh0, qhi[0], acc, 0, 0, 0);
        acc = __builtin_amdgcn_mfma_f32_16x16x32_bf16(kh0, qlo[0], acc, 0, 0, 0);
        acc = __builtin_amdgcn_mfma_f32_16x16x32_bf16(kl0, qhi[0], acc, 0, 0, 0);
        acc = __builtin_amdgcn_mfma_f32_16x16x32_bf16(kh1, qhi[1], acc, 0, 0, 0);
        acc = __builtin_amdgcn_mfma_f32_16x16x32_bf16(kh1, qlo[1], acc, 0, 0, 0);
        acc = __builtin_amdgcn_mfma_f32_16x16x32_bf16(kl1, qhi[1], acc, 0, 0, 0);
        s[cb] = acc;
    }

    // row max
    float m = -3.0e38f;
    #pragma unroll
    for (int cb = 0; cb < 16; ++cb) {
        #pragma unroll
        for (int r = 0; r < 4; ++r) m = fmaxf(m, s[cb][r]);
    }
    m = fmaxf(m, __shfl_xor(m, 16));
    m = fmaxf(m, __shfl_xor(m, 32));
    if (lane < 16) redm[wv * 16 + l15] = m;
    __syncthreads();
    float mall = redm[l15];
    #pragma unroll
    for (int w2 = 1; w2 < WAVES; ++w2) mall = fmaxf(mall, redm[w2 * 16 + l15]);

    // exp + row sum
    float sm = 0.f;
    #pragma unroll
    for (int cb = 0; cb < 16; ++cb) {
        #pragma unroll
        for (int r = 0; r < 4; ++r) {
            float e = __expf(s[cb][r] - mall);
            s[cb][r] = e;
            sm += e;
        }
    }
    sm += __shfl_xor(sm, 16);
    sm += __shfl_xor(sm, 32);
    if (lane < 16) reds[wv * 16 + l15] = sm;
    __syncthreads();
    float lsum = 0.f;
    #pragma unroll
    for (int w2 = 0; w2 < WAVES; ++w2) lsum += reds[w2 * 16 + l15];
    const float inv = 1.0f / lsum;

    // normalize -> pack P to bf16 -> stage W tile in LDS (frees s[] before PV)
    // LDS tile: row l15 (4096 B/row), 8B unit c4 = wv*64 + cb*4 + g,
    // byte = row*4096 + ((c4*8) ^ ((row&7)<<3))   [XOR keeps writes/reads 2-way]
    bf16x8 pa[8];
    const int swz = (l15 & 7) << 3;
    #pragma unroll
    for (int u = 0; u < 8; ++u) {
        f32x4 w0, w1;
        #pragma unroll
        for (int r = 0; r < 4; ++r) {
            w0[r] = s[2 * u][r]     * inv;
            w1[r] = s[2 * u + 1][r] * inv;
        }
        #pragma unroll
        for (int r = 0; r < 4; ++r) {
            pa[u][r]     = (__bf16)w0[r];
            pa[u][4 + r] = (__bf16)w1[r];
        }
        const uint2* pau = (const uint2*)&pa[u];
        int c4a = wv * 64 + (2 * u) * 4 + g;
        int c4b = c4a + 4;
        *(uint2*)(smem + l15 * 4096 + ((c4a * 8) ^ swz)) = pau[0];
        *(uint2*)(smem + l15 * 4096 + ((c4b * 8) ^ swz)) = pau[1];
    }
    __syncthreads();

    // sweep-out: row-major contiguous NT stores (1 KB per wave-instruction)
    {
        float* Wrow = Wb + (size_t)q0 * S_SZ;
        #pragma unroll
        for (int sidx = 0; sidx < 16; ++sidx) {
            int unit = sidx * 512 + tid;           // 8B units; 512 units/row
            int row  = unit >> 9;
            int c4   = unit & 511;
            uint2 u2 = *(const uint2*)(smem + row * 4096 + ((c4 * 8) ^ ((row & 7) << 3)));
            f32x4 f;
            f[0] = __uint_as_float(u2.x << 16);
            f[1] = __uint_as_float(u2.x & 0xffff0000u);
            f[2] = __uint_as_float(u2.y << 16);
            f[3] = __uint_as_float(u2.y & 0xffff0000u);
            __builtin_nontemporal_store(f, (f32x4*)(Wrow + (size_t)row * S_SZ + c4 * 4));
        }
    }

    // PV: A = packed P, B = pre-permuted V fragments (no LDS use here)
    f32x4 ctx[4];
    #pragma unroll
    for (int db = 0; db < 4; ++db) ctx[db] = (f32x4){0.f, 0.f, 0.f, 0.f};

    #pragma unroll
    for (int u = 0; u < 8; ++u) {
        size_t vbase = ((size_t)(bh * NUB + wv * 8 + u) * 4) * 64 + lane;
        #pragma unroll
        for (int db = 0; db < 4; ++db) {
            bf16x8 vb = VSW[vbase + (size_t)db * 64];
            ctx[db] = __builtin_amdgcn_mfma_f32_16x16x32_bf16(pa[u], vb, ctx[db], 0, 0, 0);
        }
    }

    // reuse W-tile LDS for cross-wave context reduction
    __syncthreads();                 // all sweep reads complete before overwrite
    float* ctxred = (float*)smem;    // [8][16][64]
    #pragma unroll
    for (int db = 0; db < 4; ++db) {
        #pragma unroll
        for (int r = 0; r < 4; ++r)
            ctxred[(wv * 16 + 4 * g + r) * 64 + 16 * db + l15] = ctx[db][r];
    }
    __syncthreads();
    {
        const int qr = tid >> 6;
        const int d  = tid & 63;
        float acc0 = 0.f, acc1 = 0.f;
        #pragma unroll
        for (int w2 = 0; w2 < WAVES; ++w2) {
            acc0 += ctxred[(w2 * 16 + qr) * 64 + d];
            acc1 += ctxred[(w2 * 16 + qr + 8) * 64 + d];
        }
        __builtin_nontemporal_store(acc0, Cb + (size_t)(q0 + qr) * D_SZ + d);
        __builtin_nontemporal_store(acc1, Cb + (size_t)(q0 + qr + 8) * D_SZ + d);
    }
}

extern "C" void kernel_launch(void* const* d_in, const int* in_sizes, int n_in,
                              void* d_out, int out_size, void* d_ws, size_t ws_size,
                              hipStream_t stream)
{
    const float* Q = (const float*)d_in[0];
    const float* K = (const float*)d_in[1];
    const float* V = (const float*)d_in[2];
    float* ctx = (float*)d_out;
    float* w   = (float*)d_out + (size_t)B_SZ * H_SZ * S_SZ * D_SZ;
    char*  ws  = (char*)d_ws;

    prep_qk<<<2048, 256, 0, stream>>>(Q, K, ws);
    prep_v <<<512,  256, 0, stream>>>(V, ws);
    attn_fused4<<<4096, 512, 0, stream>>>(ws, ctx, w);
}